// Round 12
// baseline (576.925 us; speedup 1.0000x reference)
//
#include <hip/hip_runtime.h>
#include <hip/hip_bf16.h>
#include <stdint.h>

#define E_ 8
#define B_ 4096
#define D_ 2048
#define T_ 2048
#define H_ 2048
#define KDIM 2048
#define NDIM 2048
#define NROWS (E_ * 1024 + 256)   // packed-row capacity: 8192 + tail pad

typedef __attribute__((ext_vector_type(4))) float f32x4;
typedef __attribute__((ext_vector_type(8))) unsigned short u16x8;
typedef __attribute__((ext_vector_type(8))) __bf16 bf16x8;

__device__ __forceinline__ unsigned short f2bf(float f) {
    __hip_bfloat16 h = __float2bfloat16(f);
    return __builtin_bit_cast(unsigned short, h);
}

__device__ __forceinline__ void gload_lds16(const void* g, void* lds) {
    __builtin_amdgcn_global_load_lds(
        (const __attribute__((address_space(1))) void*)g,
        (__attribute__((address_space(3))) void*)lds, 16, 0, 0);
}

// ---------------------------------------------------------------------------
// Gating: f32 logits (exact ranking), softmax, top-2, per-expert slot lists.
// Packs the 2 selected rows (held in registers) to slot-indexed bf16 A1.
// ---------------------------------------------------------------------------
__global__ __launch_bounds__(256) void moe_gating(
    const float* __restrict__ xs, const float* __restrict__ Wg,
    const float* __restrict__ bg, float* __restrict__ out_topk,
    float* __restrict__ prob_slot, int* __restrict__ counts,
    int* __restrict__ slot_of, unsigned short* __restrict__ A1)
{
    const int b = blockIdx.x;
    const int t = threadIdx.x;
    const int wave = t >> 6, lane = t & 63;
    __shared__ float red[E_][4];
    __shared__ int sh_i0, sh_i1;

    const f32x4 wg0 = ((const f32x4*)Wg)[t];
    const f32x4 wg1 = ((const f32x4*)Wg)[t + 256];

    f32x4 xa[E_], xb[E_];
    #pragma unroll
    for (int e = 0; e < E_; ++e) {
        const f32x4* xr = (const f32x4*)(xs + ((size_t)e * B_ + b) * D_);
        xa[e] = __builtin_nontemporal_load(&xr[t]);
        xb[e] = __builtin_nontemporal_load(&xr[t + 256]);
        float p = xa[e].x*wg0.x + xa[e].y*wg0.y + xa[e].z*wg0.z + xa[e].w*wg0.w
                + xb[e].x*wg1.x + xb[e].y*wg1.y + xb[e].z*wg1.z + xb[e].w*wg1.w;
        #pragma unroll
        for (int off = 32; off >= 1; off >>= 1) p += __shfl_xor(p, off);
        if (lane == 0) red[e][wave] = p;
    }
    __syncthreads();
    if (t == 0) {
        float pr[E_];
        float mx = -3.0e38f;
        #pragma unroll
        for (int e = 0; e < E_; ++e) {
            pr[e] = red[e][0] + red[e][1] + red[e][2] + red[e][3] + bg[0];
            mx = fmaxf(mx, pr[e]);
        }
        float s = 0.f;
        #pragma unroll
        for (int e = 0; e < E_; ++e) { pr[e] = expf(pr[e] - mx); s += pr[e]; }
        float inv = 1.0f / s;
        #pragma unroll
        for (int e = 0; e < E_; ++e) pr[e] *= inv;
        int i0 = 0;
        #pragma unroll
        for (int e = 1; e < E_; ++e) if (pr[e] > pr[i0]) i0 = e;
        int i1 = (i0 == 0) ? 1 : 0;
        #pragma unroll
        for (int e = 0; e < E_; ++e) { if (e != i0 && pr[e] > pr[i1]) i1 = e; }
        float p0 = pr[i0], p1 = pr[i1];
        out_topk[2*b]    = p0;
        out_topk[2*b+1]  = p1;
        prob_slot[2*b]   = p0;
        prob_slot[2*b+1] = p1;
        int pos0 = atomicAdd(&counts[i0], 1);
        slot_of[i0 * B_ + pos0] = 2*b;
        int pos1 = atomicAdd(&counts[i1], 1);
        slot_of[i1 * B_ + pos1] = 2*b + 1;
        sh_i0 = i0; sh_i1 = i1;
    }
    __syncthreads();
    const int i0 = sh_i0, i1 = sh_i1;
    f32x4 s0a = xa[0], s0b = xb[0], s1a = xa[0], s1b = xb[0];
    #pragma unroll
    for (int e = 0; e < E_; ++e) {
        if (i0 == e) { s0a = xa[e]; s0b = xb[e]; }
        if (i1 == e) { s1a = xa[e]; s1b = xb[e]; }
    }
    unsigned short* r0 = A1 + (size_t)(2*b) * D_;
    unsigned short* r1 = A1 + (size_t)(2*b+1) * D_;
    r0[4*t+0]=f2bf(s0a.x); r0[4*t+1]=f2bf(s0a.y); r0[4*t+2]=f2bf(s0a.z); r0[4*t+3]=f2bf(s0a.w);
    r0[1024+4*t+0]=f2bf(s0b.x); r0[1024+4*t+1]=f2bf(s0b.y); r0[1024+4*t+2]=f2bf(s0b.z); r0[1024+4*t+3]=f2bf(s0b.w);
    r1[4*t+0]=f2bf(s1a.x); r1[4*t+1]=f2bf(s1a.y); r1[4*t+2]=f2bf(s1a.z); r1[4*t+3]=f2bf(s1a.w);
    r1[1024+4*t+0]=f2bf(s1b.x); r1[1024+4*t+1]=f2bf(s1b.y); r1[1024+4*t+2]=f2bf(s1b.z); r1[1024+4*t+3]=f2bf(s1b.w);
}

// ---------------------------------------------------------------------------
// Work list (M-tile=256) + expert base offsets.
// ---------------------------------------------------------------------------
__global__ void build_tiles(const int* __restrict__ counts,
                            int* __restrict__ tiles, int* __restrict__ ebase)
{
    if (threadIdx.x == 0 && blockIdx.x == 0) {
        int n = 0, base = 0;
        for (int e = 0; e < E_; ++e) {
            ebase[e] = base;
            int te = (counts[e] + 255) >> 8;
            for (int m = 0; m < te; ++m) tiles[1 + n++] = (e << 16) | m;
            base += counts[e];
        }
        tiles[0] = n;
    }
}

// ---------------------------------------------------------------------------
// pack_A: permute slot-indexed A1 (bf16) -> expert-contiguous Ax (bf16).
// ---------------------------------------------------------------------------
__global__ __launch_bounds__(256) void pack_A(
    const unsigned short* __restrict__ A1, const int* __restrict__ slot_of,
    const int* __restrict__ counts, const int* __restrict__ ebase,
    const float* __restrict__ prob_slot, unsigned short* __restrict__ Ax,
    int* __restrict__ tokid, float* __restrict__ prob_pk)
{
    const int e = blockIdx.x >> 12;
    const int i = blockIdx.x & 4095;
    if (i >= counts[e]) return;
    const int slot = slot_of[e * B_ + i];
    const int g = ebase[e] + i;
    const int t = threadIdx.x;
    ((u16x8*)(Ax + (size_t)g * D_))[t] =
        ((const u16x8*)(A1 + (size_t)slot * D_))[t];
    if (t == 0) { tokid[g] = slot >> 1; prob_pk[g] = prob_slot[slot]; }
}

// ---------------------------------------------------------------------------
// Weight transpose-convert: W[e][K][N] f32 -> Wt[e][N][K] bf16, 64x64 tiles.
// DUAL variant handles both layers in one dispatch (z = layer*8 + e).
// ---------------------------------------------------------------------------
template<int DUAL>
__global__ __launch_bounds__(256) void wtrans(
    const float* __restrict__ Wa, const float* __restrict__ Wb,
    unsigned short* __restrict__ Wta, unsigned short* __restrict__ Wtb)
{
    const int z  = blockIdx.z;
    const int e  = DUAL ? (z & 7) : z;
    const float* W = (DUAL && (z >> 3)) ? Wb : Wa;
    unsigned short* Wt = (DUAL && (z >> 3)) ? Wtb : Wta;
    const int kb = blockIdx.x * 64;
    const int nb = blockIdx.y * 64;
    const int t  = threadIdx.x;
    __shared__ float tile[64][68];

    const float* src = W + ((size_t)e * KDIM + kb) * NDIM + nb;
    {
        const int kr = t >> 2, nc = (t & 3) * 16;
        #pragma unroll
        for (int j = 0; j < 4; ++j) {
            f32x4 v = __builtin_nontemporal_load(
                (const f32x4*)(src + (size_t)kr * NDIM + nc + j * 4));
            *(f32x4*)&tile[kr][nc + j * 4] = v;
        }
    }
    __syncthreads();
    {
        const int nn = t >> 2, kc = (t & 3) * 16;
        unsigned short wbuf[16];
        #pragma unroll
        for (int j = 0; j < 16; ++j) wbuf[j] = f2bf(tile[kc + j][nn]);
        unsigned short* dst = Wt + ((size_t)e * NDIM + nb + nn) * KDIM + kb + kc;
        *(u16x8*)dst       = *(const u16x8*)&wbuf[0];
        *((u16x8*)dst + 1) = *(const u16x8*)&wbuf[8];
    }
}

// ---------------------------------------------------------------------------
// 256x256 8-phase expert GEMM (m201 schedule, r3-correctness-proven), now on
// DENSE packed A. BK=64, 8 waves (2M x 4N, wave-tile 128x64), 128 KiB dbuf
// LDS, global_load_lds(16B) w/ pre-swizzled source (kblk ^= row&7), counted
// vmcnt(4) at phases 0/4 only (never 0 in-loop), setprio around MFMA.
// Per-iter stage schedule (verified WAR/RAW in r3):
//   p0:A1odd(2i+1) p1:A0even(2i+2) p2:B0even p3:B0odd p4:A0odd
//   p5:A1even(2i+3) p6:B1even p7:B1odd
// bid = mt*8+np: np = XCD, B-panel [e][np] L2-local across an expert's tiles.
// ---------------------------------------------------------------------------
#define BAR  __builtin_amdgcn_s_barrier()
#define WLG  asm volatile("s_waitcnt lgkmcnt(0)" ::: "memory")
#define WVM4 asm volatile("s_waitcnt vmcnt(4)" ::: "memory")
#define PRIO1 __builtin_amdgcn_s_setprio(1)
#define PRIO0 __builtin_amdgcn_s_setprio(0)

#define STA(BUF,P,KT) do{ \
    gload_lds16(aptr[P][0] + (KT)*64, &As[(BUF)*2048 + 0*1024 + (P)*512 + w64]); \
    gload_lds16(aptr[P][1] + (KT)*64, &As[(BUF)*2048 + 1*1024 + (P)*512 + w64]); }while(0)
#define STB(BUF,P,KT) do{ \
    gload_lds16(bptr[P][0] + (KT)*64, &Bs[(BUF)*2048 + (0*2+seg_w)*512 + (P)*256 + w3x64]); \
    gload_lds16(bptr[P][1] + (KT)*64, &Bs[(BUF)*2048 + (1*2+seg_w)*512 + (P)*256 + w3x64]); }while(0)

#define RDA(BUF,MQ) do{ \
    _Pragma("unroll") \
    for (int mf2 = 0; mf2 < 4; ++mf2) { \
        int row = wm + ((MQ)*4 + mf2) * 16 + (lane & 15); \
        int base = (BUF)*2048 + row * 8; \
        af[mf2][0] = __builtin_bit_cast(bf16x8, As[base + ((0*4 + lg) ^ (row & 7))]); \
        af[mf2][1] = __builtin_bit_cast(bf16x8, As[base + ((1*4 + lg) ^ (row & 7))]); } }while(0)
#define RDB(BUF,NQ,DST) do{ \
    _Pragma("unroll") \
    for (int nf2 = 0; nf2 < 2; ++nf2) { \
        int row = wn + ((NQ)*2 + nf2) * 16 + (lane & 15); \
        int base = (BUF)*2048 + row * 8; \
        DST[nf2][0] = __builtin_bit_cast(bf16x8, Bs[base + ((0*4 + lg) ^ (row & 7))]); \
        DST[nf2][1] = __builtin_bit_cast(bf16x8, Bs[base + ((1*4 + lg) ^ (row & 7))]); } }while(0)
#define MM(MQ,NQ,BF) do{ \
    _Pragma("unroll") \
    for (int mf2 = 0; mf2 < 4; ++mf2) \
    _Pragma("unroll") \
    for (int nf2 = 0; nf2 < 2; ++nf2) \
    _Pragma("unroll") \
    for (int kk = 0; kk < 2; ++kk) \
        acc[(MQ)*4+mf2][(NQ)*2+nf2] = __builtin_amdgcn_mfma_f32_16x16x32_bf16( \
            af[mf2][kk], BF[nf2][kk], acc[(MQ)*4+mf2][(NQ)*2+nf2], 0, 0, 0); }while(0)

template<int LAYER>
__global__ __launch_bounds__(512, 2) void moe_gemm(
    const unsigned short* __restrict__ Abuf,   // packed: Ax (L1) / hidden (L2)
    const unsigned short* __restrict__ Wt,
    const float* __restrict__ bias,
    const int* __restrict__ counts,
    const int* __restrict__ tiles,
    const int* __restrict__ ebase,
    const int* __restrict__ tokid,
    const float* __restrict__ prob_pk,
    unsigned short* __restrict__ hidden_out,
    float* __restrict__ out)
{
    const int nMt = tiles[0];
    const int bid = blockIdx.x;
    const int mt  = bid >> 3;
    const int np  = bid & 7;
    if (mt >= nMt) return;
    const int info = tiles[1 + bid >> 3 == mt ? 1 + mt - 1 + 1 - 1 + 0 + (mt) : 1 + mt]; // (kept simple below)
    const int info2 = tiles[1 + mt];
    const int e    = info2 >> 16;
    const int mloc = (info2 & 0xffff) * 256;
    const int gm0  = ebase[e] + mloc;
    const int n0   = np * 256;
    const int n_e  = counts[e];

    const int t = threadIdx.x;
    const int lane = t & 63;
    const int w = t >> 6;
    const int wm = (w >> 2) * 128;
    const int wn = (w & 3) * 64;
    const int lg = lane >> 4;

    __shared__ u16x8 As[2 * 2048];
    __shared__ u16x8 Bs[2 * 2048];

    const int swz = ((lane & 7) ^ ((lane >> 3) & 7)) * 8;
    const int rlo = lane >> 3;
    const int seg_w = w >> 2;
    const int w3x64 = (w & 3) * 64;
    const int w64 = w * 64;

    const unsigned short* aptr[2][2];
    #pragma unroll
    for (int P = 0; P < 2; ++P)
        #pragma unroll
        for (int j = 0; j < 2; ++j) {
            int rA = j * 128 + P * 64 + w * 8 + rlo;
            aptr[P][j] = Abuf + (size_t)(gm0 + rA) * KDIM + swz;
        }
    const unsigned short* bptr[2][2];
    #pragma unroll
    for (int P = 0; P < 2; ++P)
        #pragma unroll
        for (int j = 0; j < 2; ++j) {
            int sseg = j * 2 + seg_w;
            int rB = sseg * 64 + P * 32 + (w & 3) * 8 + rlo;
            bptr[P][j] = Wt + ((size_t)e * NDIM + n0 + rB) * KDIM + swz;
        }

    f32x4 acc[8][4];
    #pragma unroll
    for (int i = 0; i < 8; ++i)
        #pragma unroll
        for (int j = 0; j < 4; ++j) {
            f32x4 z = {0.f, 0.f, 0.f, 0.f};
            acc[i][j] = z;
        }
    bf16x8 af[4][2], bfe[2][2], bfo[2][2];

    // prologue: buf0 <- tile0 (A-even,B-even,B-odd,A-odd), buf1 <- tile1
    STA(0,0,0); STB(0,0,0); STB(0,1,0); STA(0,1,0);
    STA(1,0,1); STB(1,0,1); STB(1,1,1);
    asm volatile("s_waitcnt vmcnt(6)" ::: "memory");   // buf0 fully landed
    BAR;

    for (int i = 0; i < 16; ++i) {
        const int t1 = 2*i + 1;
        int t2 = 2*i + 2; if (t2 > 31) t2 = 31;
        int t3 = 2*i + 3; if (t3 > 31) t3 = 31;
        // p0
        RDA(0,0); RDB(0,0,bfe);
        STA(1,1,t1);
        WVM4; BAR; WLG; PRIO1; MM(0,0,bfe); PRIO0; BAR;
        // p1
        RDB(0,1,bfo);
        STA(0,0,t2);
        BAR; WLG; PRIO1; MM(0,1,bfo); PRIO0; BAR;
        // p2
        RDA(0,1);
        STB(0,0,t2);
        BAR; WLG; PRIO1; MM(1,0,bfe); PRIO0; BAR;
        // p3
        STB(0,1,t2);
        BAR; PRIO1; MM(1,1,bfo); PRIO0; BAR;
        // p4
        RDA(1,0); RDB(1,0,bfe);
        STA(0,1,t2);
        WVM4; BAR; WLG; PRIO1; MM(0,0,bfe); PRIO0; BAR;
        // p5
        RDB(1,1,bfo);
        STA(1,0,t3);
        BAR; WLG; PRIO1; MM(0,1,bfo); PRIO0; BAR;
        // p6
        RDA(1,1);
        STB(1,0,t3);
        BAR; WLG; PRIO1; MM(1,0,bfe); PRIO0; BAR;
        // p7
        STB(1,1,t3);
        BAR; PRIO1; MM(1,1,bfo); PRIO0; BAR;
    }
    asm volatile("s_waitcnt vmcnt(0)" ::: "memory");   // drain before LDS reuse

    // epilogue — C/D layout: col = lane&15, row = (lane>>4)*4 + reg
    #pragma unroll
    for (int mf = 0; mf < 8; ++mf) {
        #pragma unroll
        for (int rr = 0; rr < 4; ++rr) {
            const int rloc = wm + mf * 16 + ((lane >> 4) << 2) + rr;
            if (mloc + rloc >= n_e) continue;
            const int g = gm0 + rloc;
            #pragma unroll
            for (int nf = 0; nf < 4; ++nf) {
                const int col = n0 + wn + nf * 16 + (lane & 15);
                float v = acc[mf][nf][rr];
                if (LAYER == 1) {
                    v += bias[e * NDIM + col];
                    v = fmaxf(v, 0.f);
                    hidden_out[(size_t)g * H_ + col] = f2bf(v);
                } else {
                    v = (v + bias[e * NDIM + col]) * prob_pk[g];
                    atomicAdd(&out[(size_t)tokid[g] * T_ + col], v);
                }
            }
        }
    }
}

// ---------------------------------------------------------------------------
// ws layout:
//   counts@0(256) | tiles@256(512) | ebase@768(64) | slot_of@1024 |
//   prob_slot | tokid | prob_pk | A1[2B][D] | Ax[NROWS][D] |
//   hidden[NROWS][H] | Wt1 | (Wt2 if ws allows)
// ---------------------------------------------------------------------------
extern "C" void kernel_launch(void* const* d_in, const int* in_sizes, int n_in,
                              void* d_out, int out_size, void* d_ws, size_t ws_size,
                              hipStream_t stream)
{
    const float* xs = (const float*)d_in[0];
    const float* Wg = (const float*)d_in[1];
    const float* bg = (const float*)d_in[2];
    const float* W1 = (const float*)d_in[3];
    const float* b1 = (const float*)d_in[4];
    const float* W2 = (const float*)d_in[5];
    const float* b2 = (const float*)d_in[6];

    float* out      = (float*)d_out;
    float* out_topk = out + (size_t)B_ * T_;

    char* ws = (char*)d_ws;
    int*   counts    = (int*)ws;
    int*   tiles     = (int*)(ws + 256);
    int*   ebase     = (int*)(ws + 768);
    int*   slot_of   = (int*)(ws + 1024);
    float* prob_slot = (float*)(ws + 1024 + E_ * B_ * 4);
    size_t off = 1024 + (size_t)E_ * B_ * 4 + 2 * B_ * 4;
    off = (off + 255) & ~(size_t)255;
    int*   tokid   = (int*)(ws + off);   off += (size_t)NROWS * 4;
    float* prob_pk = (float*)(ws + off); off += (size_t)NROWS * 4;
    off = (off + 255) & ~(size_t)255;
    unsigned short* A1     = (unsigned short*)(ws + off); off += (size_t)2 * B_ * D_ * 2;
    unsigned short* Ax     = (unsigned short*)(ws + off); off += (size_t)NROWS * D_ * 2;
    unsigned short* hidden = (unsigned short*)(ws + off); off += (size_t)NROWS * H_ * 2;
    unsigned short* Wt1    = (unsigned short*)(ws + off); off += (size_t)E_ * KDIM * NDIM * 2;
    size_t off_big = off + (size_t)E_ * KDIM * NDIM * 2;
    unsigned short* Wt2 = (unsigned short*)(ws + off);

    const bool big = (ws_size >= off_big);

    hipMemsetAsync(counts, 0, 256, stream);
    hipMemsetAsync(out, 0, (size_t)B_ * T_ * sizeof(float), stream);

    dim3 blk(256), gblk(512);
    dim3 ggrid(39 * 8);        // worst-case 39 m-tiles x 8 n-panels
    dim3 pgrid(E_ * 4096);

    if (big) {
        dim3 tgrid(32, 32, 16);
        wtrans<1><<<tgrid, blk, 0, stream>>>(W1, W2, Wt1, Wt2);
        moe_gating<<<dim3(B_), blk, 0, stream>>>(
            xs, Wg, bg, out_topk, prob_slot, counts, slot_of, A1);
        build_tiles<<<dim3(1), dim3(64), 0, stream>>>(counts, tiles, ebase);
        pack_A<<<pgrid, blk, 0, stream>>>(
            A1, slot_of, counts, ebase, prob_slot, Ax, tokid, prob_pk);
        moe_gemm<1><<<ggrid, gblk, 0, stream>>>(
            Ax, Wt1, b1, counts, tiles, ebase, tokid, prob_pk, hidden, nullptr);
        moe_gemm<2><<<ggrid, gblk, 0, stream>>>(
            hidden, Wt2, b2, counts, tiles, ebase, tokid, prob_pk, nullptr, out);
    } else {
        dim3 tgrid(32, 32, E_);
        moe_gating<<<dim3(B_), blk, 0, stream>>>(
            xs, Wg, bg, out_topk, prob_slot, counts, slot_of, A1);
        build_tiles<<<dim3(1), dim3(64), 0, stream>>>(counts, tiles, ebase);
        pack_A<<<pgrid, blk, 0, stream>>>(
            A1, slot_of, counts, ebase, prob_slot, Ax, tokid, prob_pk);
        wtrans<0><<<tgrid, blk, 0, stream>>>(W1, nullptr, Wt1, nullptr);
        moe_gemm<1><<<ggrid, gblk, 0, stream>>>(
            Ax, Wt1, b1, counts, tiles, ebase, tokid, prob_pk, hidden, nullptr);
        wtrans<0><<<tgrid, blk, 0, stream>>>(W2, nullptr, Wt1, nullptr);
        moe_gemm<2><<<ggrid, gblk, 0, stream>>>(
            hidden, Wt1, b2, counts, tiles, ebase, tokid, prob_pk, nullptr, out);
    }
}

// Round 13
// 498.942 us; speedup vs baseline: 1.1563x; 1.1563x over previous
//
#include <hip/hip_runtime.h>
#include <hip/hip_bf16.h>
#include <stdint.h>

#define E_ 8
#define B_ 4096
#define D_ 2048
#define T_ 2048
#define H_ 2048
#define KDIM 2048
#define NDIM 2048
#define ECAP 2048                  // fixed per-expert row capacity (37 sigma)
#define NROWS (E_ * 1024 + 256)    // compact hidden capacity + tail pad

typedef __attribute__((ext_vector_type(4))) float f32x4;
typedef __attribute__((ext_vector_type(8))) unsigned short u16x8;
typedef __attribute__((ext_vector_type(8))) __bf16 bf16x8;

__device__ __forceinline__ unsigned short f2bf(float f) {
    __hip_bfloat16 h = __float2bfloat16(f);
    return __builtin_bit_cast(unsigned short, h);
}

__device__ __forceinline__ void gload_lds16(const void* g, void* lds) {
    __builtin_amdgcn_global_load_lds(
        (const __attribute__((address_space(1))) void*)g,
        (__attribute__((address_space(3))) void*)lds, 16, 0, 0);
}

// ---------------------------------------------------------------------------
// Fused prologue: blocks [0,nwt) do weight transpose-convert (both layers),
// blocks [nwt, nwt+B) do gating. Gating hides under the BW-bound wtrans.
//
// wtrans: W[e][K][N] f32 -> Wt[e][N][K] bf16, 64x64 tiles, nt loads.
// gating: f32 logits (exact ranking), softmax, top-2; writes the 2 selected
// rows (held in registers) DIRECTLY to expert-major Axf[e][ECAP][D] at the
// atomically acquired position; also tokf/probf metadata. No pack pass.
// ---------------------------------------------------------------------------
__global__ __launch_bounds__(256) void fused_pre(
    const float* __restrict__ xs, const float* __restrict__ Wg,
    const float* __restrict__ bg,
    const float* __restrict__ W1, const float* __restrict__ W2,
    unsigned short* __restrict__ Wt1, unsigned short* __restrict__ Wt2,
    float* __restrict__ out_topk, int* __restrict__ counts,
    unsigned short* __restrict__ Axf, int* __restrict__ tokf,
    float* __restrict__ probf, int nwt)
{
    const int bid = blockIdx.x;
    const int t = threadIdx.x;

    if (bid < nwt) {
        // ---------------- wtrans ----------------
        const int z   = bid >> 10;            // 0..15 (layer*8 + e)
        const int rem = bid & 1023;
        const int kb  = ((rem >> 5) & 31) << 6;
        const int nb  = (rem & 31) << 6;
        const int e   = z & 7;
        const float* W = (z >> 3) ? W2 : W1;
        unsigned short* Wt = (z >> 3) ? Wt2 : Wt1;

        __shared__ float tile[64][68];
        const float* src = W + ((size_t)e * KDIM + kb) * NDIM + nb;
        {
            const int kr = t >> 2, nc = (t & 3) * 16;
            #pragma unroll
            for (int j = 0; j < 4; ++j) {
                f32x4 v = __builtin_nontemporal_load(
                    (const f32x4*)(src + (size_t)kr * NDIM + nc + j * 4));
                *(f32x4*)&tile[kr][nc + j * 4] = v;
            }
        }
        __syncthreads();
        {
            const int nn = t >> 2, kc = (t & 3) * 16;
            unsigned short wbuf[16];
            #pragma unroll
            for (int j = 0; j < 16; ++j) wbuf[j] = f2bf(tile[kc + j][nn]);
            unsigned short* dst =
                Wt + ((size_t)e * NDIM + nb + nn) * KDIM + kb + kc;
            *(u16x8*)dst       = *(const u16x8*)&wbuf[0];
            *((u16x8*)dst + 1) = *(const u16x8*)&wbuf[8];
        }
        return;
    }

    // ---------------- gating ----------------
    const int b = bid - nwt;
    const int wave = t >> 6, lane = t & 63;
    __shared__ float red[E_][4];
    __shared__ int sh_i0, sh_i1, sh_p0, sh_p1;

    const f32x4 wg0 = ((const f32x4*)Wg)[t];
    const f32x4 wg1 = ((const f32x4*)Wg)[t + 256];

    f32x4 xa[E_], xb[E_];
    #pragma unroll
    for (int e = 0; e < E_; ++e) {
        const f32x4* xr = (const f32x4*)(xs + ((size_t)e * B_ + b) * D_);
        xa[e] = __builtin_nontemporal_load(&xr[t]);
        xb[e] = __builtin_nontemporal_load(&xr[t + 256]);
        float p = xa[e].x*wg0.x + xa[e].y*wg0.y + xa[e].z*wg0.z + xa[e].w*wg0.w
                + xb[e].x*wg1.x + xb[e].y*wg1.y + xb[e].z*wg1.z + xb[e].w*wg1.w;
        #pragma unroll
        for (int off = 32; off >= 1; off >>= 1) p += __shfl_xor(p, off);
        if (lane == 0) red[e][wave] = p;
    }
    __syncthreads();
    if (t == 0) {
        float pr[E_];
        float mx = -3.0e38f;
        #pragma unroll
        for (int e = 0; e < E_; ++e) {
            pr[e] = red[e][0] + red[e][1] + red[e][2] + red[e][3] + bg[0];
            mx = fmaxf(mx, pr[e]);
        }
        float s = 0.f;
        #pragma unroll
        for (int e = 0; e < E_; ++e) { pr[e] = expf(pr[e] - mx); s += pr[e]; }
        float inv = 1.0f / s;
        #pragma unroll
        for (int e = 0; e < E_; ++e) pr[e] *= inv;
        int i0 = 0;
        #pragma unroll
        for (int e = 1; e < E_; ++e) if (pr[e] > pr[i0]) i0 = e;
        int i1 = (i0 == 0) ? 1 : 0;
        #pragma unroll
        for (int e = 0; e < E_; ++e) { if (e != i0 && pr[e] > pr[i1]) i1 = e; }
        float p0 = pr[i0], p1 = pr[i1];
        out_topk[2*b]   = p0;
        out_topk[2*b+1] = p1;
        int pos0 = atomicAdd(&counts[i0], 1);
        int pos1 = atomicAdd(&counts[i1], 1);
        if (pos0 >= ECAP) pos0 = ECAP - 1;   // unreachable guard
        if (pos1 >= ECAP) pos1 = ECAP - 1;
        tokf[i0 * ECAP + pos0] = b;  probf[i0 * ECAP + pos0] = p0;
        tokf[i1 * ECAP + pos1] = b;  probf[i1 * ECAP + pos1] = p1;
        sh_i0 = i0; sh_i1 = i1; sh_p0 = pos0; sh_p1 = pos1;
    }
    __syncthreads();
    const int i0 = sh_i0, i1 = sh_i1;
    f32x4 s0a = xa[0], s0b = xb[0], s1a = xa[0], s1b = xb[0];
    #pragma unroll
    for (int e = 0; e < E_; ++e) {
        if (i0 == e) { s0a = xa[e]; s0b = xb[e]; }
        if (i1 == e) { s1a = xa[e]; s1b = xb[e]; }
    }
    unsigned short* r0 = Axf + (size_t)(i0 * ECAP + sh_p0) * D_;
    unsigned short* r1 = Axf + (size_t)(i1 * ECAP + sh_p1) * D_;
    r0[4*t+0]=f2bf(s0a.x); r0[4*t+1]=f2bf(s0a.y); r0[4*t+2]=f2bf(s0a.z); r0[4*t+3]=f2bf(s0a.w);
    r0[1024+4*t+0]=f2bf(s0b.x); r0[1024+4*t+1]=f2bf(s0b.y); r0[1024+4*t+2]=f2bf(s0b.z); r0[1024+4*t+3]=f2bf(s0b.w);
    r1[4*t+0]=f2bf(s1a.x); r1[4*t+1]=f2bf(s1a.y); r1[4*t+2]=f2bf(s1a.z); r1[4*t+3]=f2bf(s1a.w);
    r1[1024+4*t+0]=f2bf(s1b.x); r1[1024+4*t+1]=f2bf(s1b.y); r1[1024+4*t+2]=f2bf(s1b.z); r1[1024+4*t+3]=f2bf(s1b.w);
}

// ---------------------------------------------------------------------------
// Work list (M-tile=256) + compact hidden base offsets.
// ---------------------------------------------------------------------------
__global__ void build_tiles(const int* __restrict__ counts,
                            int* __restrict__ tiles, int* __restrict__ ebase)
{
    if (threadIdx.x == 0 && blockIdx.x == 0) {
        int n = 0, base = 0;
        for (int e = 0; e < E_; ++e) {
            ebase[e] = base;
            int c = counts[e]; if (c > ECAP) c = ECAP;
            int te = (c + 255) >> 8;
            for (int m = 0; m < te; ++m) tiles[1 + n++] = (e << 16) | m;
            base += c;
        }
        tiles[0] = n;
    }
}

// ---------------------------------------------------------------------------
// Single-layer wtrans (fallback path only).
// ---------------------------------------------------------------------------
__global__ __launch_bounds__(256) void wtrans1(
    const float* __restrict__ W, unsigned short* __restrict__ Wt)
{
    const int e  = blockIdx.z;
    const int kb = blockIdx.x * 64;
    const int nb = blockIdx.y * 64;
    const int t  = threadIdx.x;
    __shared__ float tile[64][68];

    const float* src = W + ((size_t)e * KDIM + kb) * NDIM + nb;
    {
        const int kr = t >> 2, nc = (t & 3) * 16;
        #pragma unroll
        for (int j = 0; j < 4; ++j) {
            f32x4 v = __builtin_nontemporal_load(
                (const f32x4*)(src + (size_t)kr * NDIM + nc + j * 4));
            *(f32x4*)&tile[kr][nc + j * 4] = v;
        }
    }
    __syncthreads();
    {
        const int nn = t >> 2, kc = (t & 3) * 16;
        unsigned short wbuf[16];
        #pragma unroll
        for (int j = 0; j < 16; ++j) wbuf[j] = f2bf(tile[kc + j][nn]);
        unsigned short* dst = Wt + ((size_t)e * NDIM + nb + nn) * KDIM + kb + kc;
        *(u16x8*)dst       = *(const u16x8*)&wbuf[0];
        *((u16x8*)dst + 1) = *(const u16x8*)&wbuf[8];
    }
}

// ---------------------------------------------------------------------------
// 256x256 expert GEMM — r11 core (best measured), dense A both layers.
// BK=32, 1024 threads = 16 waves (4x4, wave-tile 64x64), 4 LDS buffer pairs
// (128 KB), depth-3 counted vmcnt(4) (never 0 in-loop), one barrier/K-tile.
// Involution swizzle u ^= (row>>1)&3, DMA source pre-swizzled (rule #21),
// 0 bank conflicts measured. A base: L1 = e*ECAP+mloc (fixed-capacity Axf),
// L2 = ebase[e]+mloc (compact hidden). Epilogue maps rows to tokf/probf via
// the fixed index e*ECAP + row-within-expert.
// ---------------------------------------------------------------------------
#define BAR  __builtin_amdgcn_s_barrier()

template<int LAYER>
__global__ __launch_bounds__(1024, 4) void moe_gemm(
    const unsigned short* __restrict__ Abuf,   // Axf (L1) / hidden (L2)
    const unsigned short* __restrict__ Wt,
    const float* __restrict__ bias,
    const int* __restrict__ counts,
    const int* __restrict__ tiles,
    const int* __restrict__ ebase,
    const int* __restrict__ tokf,
    const float* __restrict__ probf,
    unsigned short* __restrict__ hidden_out,
    float* __restrict__ out)
{
    const int nMt = tiles[0];
    const int bid = blockIdx.x;
    const int mt  = bid >> 3;
    const int np  = bid & 7;
    if (mt >= nMt) return;
    const int info = tiles[1 + mt];
    const int e    = info >> 16;
    const int mloc = (info & 0xffff) * 256;
    const int arow0 = (LAYER == 1) ? (e * ECAP + mloc) : (ebase[e] + mloc);
    const int n0   = np * 256;
    int n_e = counts[e]; if (n_e > ECAP) n_e = ECAP;

    const int t = threadIdx.x;
    const int lane = t & 63;
    const int w = t >> 6;
    const int wm = (w >> 2) * 64;
    const int wn = (w & 3) * 64;
    const int lg = lane >> 4;          // k-unit 0..3 (8 bf16 each)

    __shared__ u16x8 As[4 * 1024];     // 4 bufs x 256 rows x 4 units (64 KB)
    __shared__ u16x8 Bs[4 * 1024];

    // staging: thread t -> row t>>2 (0..255), LDS unit t&3 (linear dest per
    // wave: 64 lanes = 1 KB). Source k-unit pre-swizzled (involution):
    const int ksw = (((t & 3) ^ ((t >> 3) & 3)) << 3);   // bf16 elems
    const unsigned short* aptr = Abuf + (size_t)(arow0 + (t >> 2)) * KDIM + ksw;
    const unsigned short* bptr =
        Wt + ((size_t)e * NDIM + n0 + (t >> 2)) * KDIM + ksw;

#define STG(BUF, KT) do{ \
    gload_lds16(aptr + (KT)*32, &As[(BUF)*1024 + w*64]); \
    gload_lds16(bptr + (KT)*32, &Bs[(BUF)*1024 + w*64]); }while(0)

    f32x4 acc[4][4];
    #pragma unroll
    for (int i = 0; i < 4; ++i)
        #pragma unroll
        for (int j = 0; j < 4; ++j) {
            f32x4 z = {0.f, 0.f, 0.f, 0.f};
            acc[i][j] = z;
        }

    // prologue: 3 K-tiles in flight (6 loads/thread)
    STG(0, 0); STG(1, 1); STG(2, 2);

    const int usw = (lane >> 1) & 3;   // = (frag_row>>1)&3
    for (int kt = 0; kt < 64; ++kt) {
        asm volatile("s_waitcnt vmcnt(4)" ::: "memory");   // tile kt landed
        BAR;
        int tn = kt + 3; if (tn > 63) tn = 63;             // clamped dummy tail
        STG((kt + 3) & 3, tn);

        const int base = (kt & 3) * 1024;
        bf16x8 af[4];
        #pragma unroll
        for (int mi = 0; mi < 4; ++mi) {
            const int row = wm + mi * 16 + (lane & 15);
            af[mi] = __builtin_bit_cast(bf16x8, As[base + row * 4 + (lg ^ usw)]);
        }
        #pragma unroll
        for (int ni = 0; ni < 4; ++ni) {
            const int row = wn + ni * 16 + (lane & 15);
            bf16x8 bq = __builtin_bit_cast(bf16x8, Bs[base + row * 4 + (lg ^ usw)]);
            #pragma unroll
            for (int mi = 0; mi < 4; ++mi)
                acc[mi][ni] = __builtin_amdgcn_mfma_f32_16x16x32_bf16(
                    af[mi], bq, acc[mi][ni], 0, 0, 0);
        }
    }
    asm volatile("s_waitcnt vmcnt(0)" ::: "memory");   // drain dummies

    // epilogue — C/D layout: col = lane&15, row = (lane>>4)*4 + reg
    #pragma unroll
    for (int mi = 0; mi < 4; ++mi) {
        #pragma unroll
        for (int rr = 0; rr < 4; ++rr) {
            const int rloc = wm + mi * 16 + ((lane >> 4) << 2) + rr;
            if (mloc + rloc >= n_e) continue;
            #pragma unroll
            for (int ni = 0; ni < 4; ++ni) {
                const int col = n0 + wn + ni * 16 + (lane & 15);
                float v = acc[mi][ni][rr];
                if (LAYER == 1) {
                    v += bias[e * NDIM + col];
                    v = fmaxf(v, 0.f);
                    hidden_out[(size_t)(ebase[e] + mloc + rloc) * H_ + col] = f2bf(v);
                } else {
                    const int f = e * ECAP + mloc + rloc;
                    v = (v + bias[e * NDIM + col]) * probf[f];
                    atomicAdd(&out[(size_t)tokf[f] * T_ + col], v);
                }
            }
        }
    }
#undef STG
}

// ---------------------------------------------------------------------------
// ws layout:
//   counts@0(256) | tiles@256(512) | ebase@768(256) | tokf@1024(64K) |
//   probf(64K) | Axf[E][ECAP][D] bf16 (67MB) | hidden[NROWS][H] bf16 (35MB) |
//   Wt1 (67MB) | (Wt2 67MB if ws allows)
// ---------------------------------------------------------------------------
extern "C" void kernel_launch(void* const* d_in, const int* in_sizes, int n_in,
                              void* d_out, int out_size, void* d_ws, size_t ws_size,
                              hipStream_t stream)
{
    const float* xs = (const float*)d_in[0];
    const float* Wg = (const float*)d_in[1];
    const float* bg = (const float*)d_in[2];
    const float* W1 = (const float*)d_in[3];
    const float* b1 = (const float*)d_in[4];
    const float* W2 = (const float*)d_in[5];
    const float* b2 = (const float*)d_in[6];

    float* out      = (float*)d_out;
    float* out_topk = out + (size_t)B_ * T_;

    char* ws = (char*)d_ws;
    int*   counts = (int*)ws;
    int*   tiles  = (int*)(ws + 256);
    int*   ebase  = (int*)(ws + 768);
    int*   tokf   = (int*)(ws + 1024);
    float* probf  = (float*)(ws + 1024 + E_ * ECAP * 4);
    size_t off = 1024 + (size_t)E_ * ECAP * 8;
    off = (off + 255) & ~(size_t)255;
    unsigned short* Axf    = (unsigned short*)(ws + off); off += (size_t)E_ * ECAP * D_ * 2;
    unsigned short* hidden = (unsigned short*)(ws + off); off += (size_t)NROWS * H_ * 2;
    unsigned short* Wt1    = (unsigned short*)(ws + off); off += (size_t)E_ * KDIM * NDIM * 2;
    size_t off_big = off + (size_t)E_ * KDIM * NDIM * 2;
    unsigned short* Wt2 = (unsigned short*)(ws + off);

    const bool big = (ws_size >= off_big);

    hipMemsetAsync(counts, 0, 256, stream);
    hipMemsetAsync(out, 0, (size_t)B_ * T_ * sizeof(float), stream);

    dim3 blk(256), gblk(1024);
    dim3 ggrid(39 * 8);        // worst-case 39 m-tiles x 8 n-panels

    if (big) {
        const int nwt = 16 * 1024;         // 16 z-slices x 32x32 tiles
        fused_pre<<<dim3(nwt + B_), blk, 0, stream>>>(
            xs, Wg, bg, W1, W2, Wt1, Wt2, out_topk, counts, Axf, tokf, probf, nwt);
        build_tiles<<<dim3(1), dim3(64), 0, stream>>>(counts, tiles, ebase);
        moe_gemm<1><<<ggrid, gblk, 0, stream>>>(
            Axf, Wt1, b1, counts, tiles, ebase, tokf, probf, hidden, nullptr);
        moe_gemm<2><<<ggrid, gblk, 0, stream>>>(
            hidden, Wt2, b2, counts, tiles, ebase, tokf, probf, nullptr, out);
    } else {
        dim3 tgrid(32, 32, E_);
        fused_pre<<<dim3(B_), blk, 0, stream>>>(      // gating only (nwt=0)
            xs, Wg, bg, W1, W2, Wt1, Wt1, out_topk, counts, Axf, tokf, probf, 0);
        build_tiles<<<dim3(1), dim3(64), 0, stream>>>(counts, tiles, ebase);
        wtrans1<<<tgrid, blk, 0, stream>>>(W1, Wt1);
        moe_gemm<1><<<ggrid, gblk, 0, stream>>>(
            Axf, Wt1, b1, counts, tiles, ebase, tokf, probf, hidden, nullptr);
        wtrans1<<<tgrid, blk, 0, stream>>>(W2, Wt1);
        moe_gemm<2><<<ggrid, gblk, 0, stream>>>(
            hidden, Wt1, b2, counts, tiles, ebase, tokf, probf, nullptr, out);
    }
}